// Round 16
// baseline (186.741 us; speedup 1.0000x reference)
//
#include <hip/hip_runtime.h>
#include <math.h>

namespace {

constexpr int kB = 512, kI = 1152, kD = 8, kJ = 10, kC = 16;
constexpr int THREADS = 512;             // 8 waves
constexpr int GRP = THREADS / 4;         // 128 i-groups; 4 threads (c4) per i
constexpr int ROWS = kI / GRP;           // 9 rows per thread
constexpr int NW = THREADS / 64;         // 8 waves
constexpr int TB = 2;                    // batches per block -> W traffic halves
constexpr float EPS = 1e-7f;

// Round-15: round-14's register-resident structure at TB=2.
// Round-14 evidence: dur 143us vs W-L2-traffic floor 82us (3 GB @ ~37 TB/s)
// with VALUBusy 29% / occupancy 66% -> L2 BW on W is now the binding term.
// W traffic scales 1/TB; TB=2 -> 1.5 GB, floor 41us.
// Why TB=2 won't spill this time (vs rounds 3-7): phase 2 is the lean fused
// 3-pass (round 12, ~3x fewer live temps) and per-row sched_barrier(0)
// (round 14: VGPR 128->40) pins the scheduler's load hoisting. Live set:
// xh 72 + bl 18 + temps ~25 = ~115 < 128.
__launch_bounds__(THREADS)
__global__ void digitcaps_fused(const float* __restrict__ x,
                                const float* __restrict__ W,
                                float* __restrict__ out) {
  __shared__ float sredS[TB][NW][kC];    // 1 KB per-wave s partials
  __shared__ float sredZ[TB][NW];
  __shared__ float vfac[TB][kC];         // v = fac*s broadcast

  const int t    = threadIdx.x;
  const int lane = t & 63;
  const int wid  = t >> 6;
  const int c4   = t & 3;
  const int g    = t >> 2;               // 0..127

  const int bid = blockIdx.x;
  const int j   = bid >> 8;              // j-major: 256 blocks share W[j] in L2
  const int b0  = (bid & 255) * TB;

  float xh[TB][ROWS][4];                 // register-resident x_hat (72 floats)

  // ---------------- Phase 1: both batches share every W load ----------------
  #pragma unroll
  for (int it = 0; it < ROWS; ++it) {
    const int i = it * GRP + g;
    const float* Wp = W + (size_t)(j * kI + i) * (kD * kC) + (c4 << 2);
    float xr[TB][kD];
    #pragma unroll
    for (int tb = 0; tb < TB; ++tb) {
      const float4* xp = reinterpret_cast<const float4*>(
          x + (size_t)((b0 + tb) * kI + i) * kD);
      const float4 v0 = xp[0], v1 = xp[1];
      xr[tb][0] = v0.x; xr[tb][1] = v0.y; xr[tb][2] = v0.z; xr[tb][3] = v0.w;
      xr[tb][4] = v1.x; xr[tb][5] = v1.y; xr[tb][6] = v1.z; xr[tb][7] = v1.w;
    }
    float a[TB][4] = {};
    #pragma unroll
    for (int d = 0; d < kD; ++d) {
      const float4 w = *reinterpret_cast<const float4*>(Wp + d * kC);
      #pragma unroll
      for (int tb = 0; tb < TB; ++tb) {
        a[tb][0] += xr[tb][d] * w.x;
        a[tb][1] += xr[tb][d] * w.y;
        a[tb][2] += xr[tb][d] * w.z;
        a[tb][3] += xr[tb][d] * w.w;
      }
    }
    #pragma unroll
    for (int tb = 0; tb < TB; ++tb) {
      xh[tb][it][0] = a[tb][0]; xh[tb][it][1] = a[tb][1];
      xh[tb][it][2] = a[tb][2]; xh[tb][it][3] = a[tb][3];
    }
    // Pin scheduling per row: caps in-flight load demand (round 14: this is
    // what keeps VGPR at ~live-set instead of spilling).
    __builtin_amdgcn_sched_barrier(0);
  }

  // ---------------- Phase 2: 3 fused routing passes -------------------------
  float bl[TB][ROWS];
  #pragma unroll
  for (int tb = 0; tb < TB; ++tb)
    #pragma unroll
    for (int r = 0; r < ROWS; ++r) bl[tb][r] = 0.f;

  #pragma unroll
  for (int pass = 0; pass < 3; ++pass) {
    float4 vv[TB];
    if (pass > 0) {
      #pragma unroll
      for (int tb = 0; tb < TB; ++tb)
        vv[tb] = *reinterpret_cast<const float4*>(&vfac[tb][c4 * 4]);
    }

    float zp[TB] = {}, sp[TB][4] = {};
    #pragma unroll
    for (int r = 0; r < ROWS; ++r) {
      #pragma unroll
      for (int tb = 0; tb < TB; ++tb) {
        if (pass == 0) {
          // softmax(0) uniform: plain row-sum, no exp.
          sp[tb][0] += xh[tb][r][0]; sp[tb][1] += xh[tb][r][1];
          sp[tb][2] += xh[tb][r][2]; sp[tb][3] += xh[tb][r][3];
        } else {
          float dp = vv[tb].x * xh[tb][r][0] + vv[tb].y * xh[tb][r][1]
                   + vv[tb].z * xh[tb][r][2] + vv[tb].w * xh[tb][r][3];
          dp += __shfl_xor(dp, 1, 64);   // sum across c4 (same row)
          dp += __shfl_xor(dp, 2, 64);
          bl[tb][r] += dp;
          const float e = __expf(bl[tb][r]);  // |b| <= 2|v||xhat| < 6
          zp[tb]    += e;
          sp[tb][0] += e * xh[tb][r][0]; sp[tb][1] += e * xh[tb][r][1];
          sp[tb][2] += e * xh[tb][r][2]; sp[tb][3] += e * xh[tb][r][3];
        }
      }
    }
    #pragma unroll
    for (int off = 4; off < 64; off <<= 1) {   // reduce over g within wave
      #pragma unroll
      for (int tb = 0; tb < TB; ++tb) {
        sp[tb][0] += __shfl_xor(sp[tb][0], off, 64);
        sp[tb][1] += __shfl_xor(sp[tb][1], off, 64);
        sp[tb][2] += __shfl_xor(sp[tb][2], off, 64);
        sp[tb][3] += __shfl_xor(sp[tb][3], off, 64);
        if (pass > 0) zp[tb] += __shfl_xor(zp[tb], off, 64);
      }
    }
    if (lane < 4) {                            // lane == c4 holds its partial
      #pragma unroll
      for (int tb = 0; tb < TB; ++tb) {
        float4 v4;
        v4.x = sp[tb][0]; v4.y = sp[tb][1]; v4.z = sp[tb][2]; v4.w = sp[tb][3];
        *reinterpret_cast<float4*>(&sredS[tb][wid][lane * 4]) = v4;
      }
    }
    if (pass > 0 && lane == 0) {
      #pragma unroll
      for (int tb = 0; tb < TB; ++tb) sredZ[tb][wid] = zp[tb];
    }
    __syncthreads();                           // B1: partials ready

    // --- reducer: 32 threads (16 per batch) combine, squash, publish ---
    if (t < TB * kC) {
      const int tb = t >> 4, c = t & 15;
      float sr = 0.f;
      #pragma unroll
      for (int w = 0; w < NW; ++w) sr += sredS[tb][w][c];
      float Z;
      if (pass == 0) {
        Z = (float)kI;
      } else {
        Z = 0.f;
        #pragma unroll
        for (int w = 0; w < NW; ++w) Z += sredZ[tb][w];
      }
      const float sc = sr / Z;
      float pq = sc * sc;                      // |s|^2 within each 16-group
      pq += __shfl_xor(pq, 1, 64);
      pq += __shfl_xor(pq, 2, 64);
      pq += __shfl_xor(pq, 4, 64);
      pq += __shfl_xor(pq, 8, 64);
      const float nrm = sqrtf(pq);
      const float fac = pq / ((1.f + pq) * (nrm + EPS));
      const float vc = fac * sc;               // v[c]
      if (pass < 2) vfac[tb][c] = vc;
      else out[((size_t)(b0 + tb) * kJ + j) * kC + c] = vc;
    }
    __syncthreads();                           // B2: vfac ready, sred reusable
    // Races: sredS/Z written pre-B1 of pass k, read between B1/B2, rewritten
    // pre-B1 of pass k+1 (after B2). vfac written between B1/B2, read after
    // B2 by pass k+1. Safe.
  }
}

}  // namespace

extern "C" void kernel_launch(void* const* d_in, const int* in_sizes, int n_in,
                              void* d_out, int out_size, void* d_ws, size_t ws_size,
                              hipStream_t stream) {
  (void)in_sizes; (void)n_in; (void)d_ws; (void)ws_size; (void)out_size;
  const float* x = reinterpret_cast<const float*>(d_in[0]);
  const float* W = reinterpret_cast<const float*>(d_in[1]);
  float* out = reinterpret_cast<float*>(d_out);
  const int grid = (kB / TB) * kJ;  // 2560 blocks, j-major
  digitcaps_fused<<<grid, THREADS, 0, stream>>>(x, W, out);
}